// Round 1
// baseline (11832.740 us; speedup 1.0000x reference)
//
#include <hip/hip_runtime.h>
#include <hip/hip_bf16.h>
#include <cstdint>
#include <cstddef>

namespace {

constexpr int S_LEN  = 256;
constexpr int BATCH  = 256;
constexpr int NH     = 512;
constexpr int NE     = 256;
constexpr int NSTEPS = 127;          // TGT_LEN-1
constexpr int KX     = NE + 2*NH;    // 1280
constexpr int N1     = 3*NH;         // 1536  [Wo;Wz;Wr]
constexpr size_t SB        = (size_t)S_LEN * BATCH;   // 65536
constexpr size_t SRC_ELEMS = SB * NH;                 // 33,554,432

typedef __attribute__((ext_vector_type(8))) short  short8v;
typedef __attribute__((ext_vector_type(4))) float  float4v;

__device__ __forceinline__ float bf2f(unsigned short u) {
  union { unsigned int i; float f; } c; c.i = ((unsigned int)u) << 16; return c.f;
}
__device__ __forceinline__ unsigned short f2bf(float f) {
  union { float f; unsigned int i; } c; c.f = f;
  unsigned int x = c.i;
  return (unsigned short)((x + 0x7FFFu + ((x >> 16) & 1u)) >> 16);
}
__device__ __forceinline__ float fast_tanh(float x) {
  float ax = __builtin_fabsf(x);
  float e  = __expf(-2.f * ax);
  float r  = (1.f - e) * __builtin_amdgcn_rcpf(1.f + e);
  return x < 0.f ? -r : r;
}
__device__ __forceinline__ float fast_sigmoid(float x) {
  return __builtin_amdgcn_rcpf(1.f + __expf(-x));
}

// ---------------- prologue: conversions ----------------

__global__ void k_conv_src(const float* __restrict__ src, unsigned short* __restrict__ dst) {
  size_t i = (size_t)blockIdx.x * blockDim.x + threadIdx.x;
  size_t stride = (size_t)gridDim.x * blockDim.x;
  for (size_t j = i * 4; j < SRC_ELEMS; j += stride * 4) {
    float4 v = *(const float4*)(src + j);
    dst[j+0] = f2bf(v.x); dst[j+1] = f2bf(v.y);
    dst[j+2] = f2bf(v.z); dst[j+3] = f2bf(v.w);
  }
}

__global__ void k_conv_w(const float* __restrict__ Wo, const float* __restrict__ Wz,
                         const float* __restrict__ Wr, const float* __restrict__ Wn,
                         const float* __restrict__ Wa,
                         const float* __restrict__ Wob, const float* __restrict__ Wzb,
                         const float* __restrict__ Wrb,
                         unsigned short* __restrict__ W1, unsigned short* __restrict__ WnB,
                         unsigned short* __restrict__ Was, unsigned short* __restrict__ Wae,
                         float* __restrict__ b1) {
  const int TOT_W1 = N1 * KX;     // 1,966,080
  const int TOT_WN = NH * KX;     //   655,360
  const int TOT_WA = NH * NH;     //   262,144
  const int total  = TOT_W1 + TOT_WN + 2*TOT_WA + N1;
  int i = blockIdx.x * blockDim.x + threadIdx.x;
  int stride = gridDim.x * blockDim.x;
  for (; i < total; i += stride) {
    int idx = i;
    if (idx < TOT_W1) {
      int row = idx / KX, col = idx % KX;
      float v = (row < NH) ? Wo[row*KX+col]
              : (row < 2*NH) ? Wz[(row-NH)*KX+col]
                             : Wr[(row-2*NH)*KX+col];
      W1[idx] = f2bf(v);
    } else if ((idx -= TOT_W1) < TOT_WN) {
      WnB[idx] = f2bf(Wn[idx]);
    } else if ((idx -= TOT_WN) < TOT_WA) {
      int g = idx / NH, j = idx % NH;
      Was[idx] = f2bf(Wa[g*(2*NH) + j]);
    } else if ((idx -= TOT_WA) < TOT_WA) {
      int g = idx / NH, h = idx % NH;
      Wae[idx] = f2bf(Wa[g*(2*NH) + NH + h]);
    } else {
      idx -= TOT_WA;
      b1[idx] = (idx < NH) ? Wob[idx] : (idx < 2*NH) ? Wzb[idx-NH] : Wrb[idx-2*NH];
    }
  }
}

__global__ void k_emb(const int* __restrict__ tgt, const float* __restrict__ table,
                      unsigned short* __restrict__ emb) {
  const int total = NSTEPS * BATCH * NE;
  int i = blockIdx.x * blockDim.x + threadIdx.x;
  int stride = gridDim.x * blockDim.x;
  for (; i < total; i += stride) {
    int e  = i & (NE - 1);
    int tb = i >> 8;            // t*BATCH + b
    int sym = tgt[tb];
    emb[i] = f2bf(table[sym * NE + e]);
  }
}

// s0 = tanh(src_enc[0] @ Ws_w^T + Ws_b); also seed x = [emb0 | s0 | ?]
__global__ __launch_bounds__(256) void k_s0(
    const float* __restrict__ src, const float* __restrict__ Wsw,
    const float* __restrict__ Wsb, const unsigned short* __restrict__ emb0,
    float* __restrict__ s_f32, unsigned short* __restrict__ x) {
  __shared__ float sv[NH];
  const int b = blockIdx.x, tid = threadIdx.x;
  sv[tid]       = src[(size_t)b*NH + tid];
  sv[tid + 256] = src[(size_t)b*NH + tid + 256];
  __syncthreads();
  for (int j = tid; j < NH; j += 256) {
    float acc = Wsb[j];
    const float* wr = Wsw + (size_t)j*NH;
    #pragma unroll 8
    for (int h = 0; h < NH; h++) acc += sv[h] * wr[h];
    float s = fast_tanh(acc);
    s_f32[b*NH + j]     = s;
    x[b*KX + NE + j]    = f2bf(s);
  }
  if (tid < NE) x[b*KX + tid] = emb0[b*NE + tid];
}

// ---------------- MFMA GEMM:  C[m,n] = sum_k A[m,k]*B[n,k] (+bias[n]) ----------------
// 64x64 tile, 4 waves (2x2 of 32x32), BK=32, bf16 in, f32 accum.
template<bool OUT_BF16, bool HAS_BIAS>
__global__ __launch_bounds__(256) void k_gemm(
    const unsigned short* __restrict__ A, int lda,
    const unsigned short* __restrict__ B, int ldb,
    void* __restrict__ C, int ldc,
    const float* __restrict__ bias, int K) {
  __shared__ alignas(16) unsigned short As[64][32];
  __shared__ alignas(16) unsigned short Bs[64][32];
  const int tid  = threadIdx.x;
  const int m0   = blockIdx.x * 64, n0 = blockIdx.y * 64;
  const int lane = tid & 63, wave = tid >> 6;
  const int wm   = (wave >> 1) * 32, wn = (wave & 1) * 32;
  const int srow = tid >> 2, scol = (tid & 3) * 8;
  const int fr   = lane & 15, kq = lane >> 4;
  float4v acc00 = {0.f,0.f,0.f,0.f}, acc01 = {0.f,0.f,0.f,0.f};
  float4v acc10 = {0.f,0.f,0.f,0.f}, acc11 = {0.f,0.f,0.f,0.f};
  const unsigned short* Aptr = A + (size_t)(m0 + srow) * lda + scol;
  const unsigned short* Bptr = B + (size_t)(n0 + srow) * ldb + scol;
  for (int k0 = 0; k0 < K; k0 += 32) {
    *(short8v*)&As[srow][scol] = *(const short8v*)(Aptr + k0);
    *(short8v*)&Bs[srow][scol] = *(const short8v*)(Bptr + k0);
    __syncthreads();
    short8v a0 = *(const short8v*)&As[wm + fr][kq*8];
    short8v a1 = *(const short8v*)&As[wm + 16 + fr][kq*8];
    short8v b0 = *(const short8v*)&Bs[wn + fr][kq*8];
    short8v b1 = *(const short8v*)&Bs[wn + 16 + fr][kq*8];
    acc00 = __builtin_amdgcn_mfma_f32_16x16x32_bf16(a0, b0, acc00, 0, 0, 0);
    acc01 = __builtin_amdgcn_mfma_f32_16x16x32_bf16(a0, b1, acc01, 0, 0, 0);
    acc10 = __builtin_amdgcn_mfma_f32_16x16x32_bf16(a1, b0, acc10, 0, 0, 0);
    acc11 = __builtin_amdgcn_mfma_f32_16x16x32_bf16(a1, b1, acc11, 0, 0, 0);
    __syncthreads();
  }
  const int rq = lane >> 4;
  #pragma unroll
  for (int am = 0; am < 2; am++) {
    float4v accb0 = am ? acc10 : acc00;
    float4v accb1 = am ? acc11 : acc01;
    #pragma unroll
    for (int r = 0; r < 4; r++) {
      int row = m0 + wm + am*16 + rq*4 + r;
      int c0  = n0 + wn + fr;
      int c1  = n0 + wn + 16 + fr;
      float v0 = accb0[r], v1 = accb1[r];
      if (HAS_BIAS) { v0 += bias[c0]; v1 += bias[c1]; }
      if (OUT_BF16) {
        ((unsigned short*)C)[(size_t)row*ldc + c0] = f2bf(v0);
        ((unsigned short*)C)[(size_t)row*ldc + c1] = f2bf(v1);
      } else {
        ((float*)C)[(size_t)row*ldc + c0] = v0;
        ((float*)C)[(size_t)row*ldc + c1] = v1;
      }
    }
  }
}

// ---------------- per-step: attention (scores + softmax + context) ----------------
__global__ __launch_bounds__(512) void k_attn(
    const unsigned short* __restrict__ ep,    // (S*B, NH) bf16
    const unsigned short* __restrict__ srcb,  // (S*B, NH) bf16
    const float* __restrict__ sWa,            // (B, NH) f32
    const float* __restrict__ va,             // (NH,)
    const int* __restrict__ slen,             // (B,)
    float* __restrict__ attn_out,             // (B, S) for this t
    unsigned short* __restrict__ x) {         // write ci at x[b, NE+NH ..]
  __shared__ float q[NH];
  __shared__ float vas[NH];
  __shared__ float ei[S_LEN];
  __shared__ float ai[S_LEN];
  __shared__ float red[8];
  const int b = blockIdx.x, tid = threadIdx.x;
  const int lane = tid & 63, wave = tid >> 6;
  q[tid]   = sWa[b*NH + tid];
  vas[tid] = va[tid];
  __syncthreads();
  const int len = slen[b];

  // scores
  for (int s = wave; s < S_LEN; s += 8) {
    const unsigned short* p = ep + ((size_t)s*BATCH + b)*NH + lane*8;
    short8v v = *(const short8v*)p;
    float acc = 0.f;
    const int g0 = lane*8;
    #pragma unroll
    for (int j = 0; j < 8; j++) {
      float hv = fast_tanh(bf2f((unsigned short)v[j]) + q[g0+j]);
      acc += hv * vas[g0+j];
    }
    #pragma unroll
    for (int off = 32; off > 0; off >>= 1) acc += __shfl_xor(acc, off, 64);
    if (lane == 0) ei[s] = (s < len) ? acc : -3.0e38f;
  }
  __syncthreads();

  // softmax over s
  float e = (tid < S_LEN) ? ei[tid] : -3.0e38f;
  float m = e;
  #pragma unroll
  for (int off = 32; off > 0; off >>= 1) m = fmaxf(m, __shfl_xor(m, off, 64));
  if (lane == 0) red[wave] = m;
  __syncthreads();
  m = red[0];
  #pragma unroll
  for (int w = 1; w < 8; w++) m = fmaxf(m, red[w]);
  float p = (tid < S_LEN) ? __expf(e - m) : 0.f;
  float sum = p;
  #pragma unroll
  for (int off = 32; off > 0; off >>= 1) sum += __shfl_xor(sum, off, 64);
  __syncthreads();                 // red re-use barrier
  if (lane == 0) red[wave] = sum;
  __syncthreads();
  float tot = red[0];
  #pragma unroll
  for (int w = 1; w < 8; w++) tot += red[w];
  float inv = __builtin_amdgcn_rcpf(tot);
  if (tid < S_LEN) {
    float a = p * inv;
    ai[tid] = a;
    attn_out[(size_t)b*S_LEN + tid] = a;
  }
  __syncthreads();

  // context: ci[h] = sum_s ai[s]*src[s,b,h]
  float acc = 0.f;
  const unsigned short* sp = srcb + (size_t)b*NH + tid;
  #pragma unroll 8
  for (int s = 0; s < S_LEN; s++) acc += ai[s] * bf2f(sp[(size_t)s * BATCH * NH]);
  x[b*KX + NE + NH + tid] = f2bf(acc);
}

// ---------------- per-step: gates (after GEMM over [Wo;Wz;Wr]) ----------------
__global__ __launch_bounds__(512) void k_mid(
    const float* __restrict__ Y, const float* __restrict__ s_f32,
    float* __restrict__ dec_out_t, float* __restrict__ zi,
    unsigned short* __restrict__ x) {
  const int b = blockIdx.x, tid = threadIdx.x;   // tid covers NH=512
  dec_out_t[(size_t)b*NH + tid] = Y[(size_t)b*N1 + tid];
  zi[b*NH + tid] = fast_sigmoid(Y[(size_t)b*N1 + NH + tid]);
  float r = fast_sigmoid(Y[(size_t)b*N1 + 2*NH + tid]);
  x[b*KX + NE + tid] = f2bf(r * s_f32[b*NH + tid]);   // xn middle = ri*s
}

// ---------------- per-step: state update ----------------
__global__ __launch_bounds__(512) void k_final(
    const float* __restrict__ npre, const float* __restrict__ zi,
    float* __restrict__ s_f32, float* __restrict__ dec_states_t,
    unsigned short* __restrict__ x, const unsigned short* __restrict__ emb_next,
    int has_next) {
  const int b = blockIdx.x, tid = threadIdx.x;
  float n  = fast_tanh(npre[b*NH + tid]);
  float z  = zi[b*NH + tid];
  float so = s_f32[b*NH + tid];
  float sn = (1.f - z)*so + z*n;
  dec_states_t[(size_t)b*NH + tid] = so;
  s_f32[b*NH + tid]  = sn;
  x[b*KX + NE + tid] = f2bf(sn);
  if (has_next && tid < NE) x[b*KX + tid] = emb_next[b*NE + tid];
}

} // namespace

extern "C" void kernel_launch(void* const* d_in, const int* in_sizes, int n_in,
                              void* d_out, int out_size, void* d_ws, size_t ws_size,
                              hipStream_t stream) {
  const float* src_enc  = (const float*)d_in[0];
  const int*   tgt      = (const int*)d_in[1];
  const int*   slen     = (const int*)d_in[2];
  const float* emb_tab  = (const float*)d_in[3];
  const float* Wsw      = (const float*)d_in[4];
  const float* Wsb      = (const float*)d_in[5];
  const float* Wzw      = (const float*)d_in[6];
  const float* Wzb      = (const float*)d_in[7];
  const float* Wrw      = (const float*)d_in[8];
  const float* Wrb      = (const float*)d_in[9];
  const float* Wnw      = (const float*)d_in[10];
  const float* Wnb      = (const float*)d_in[11];
  const float* Waw      = (const float*)d_in[12];
  const float* Wab      = (const float*)d_in[13];
  const float* vaw      = (const float*)d_in[14];
  const float* Wow      = (const float*)d_in[15];
  const float* Wob      = (const float*)d_in[16];

  char* ws = (char*)d_ws;
  size_t off = 0;
  auto alloc = [&](size_t bytes) -> void* {
    void* p = ws + off;
    off = (off + bytes + 255) & ~(size_t)255;
    return p;
  };
  unsigned short* src_bf = (unsigned short*)alloc(SRC_ELEMS * 2);
  unsigned short* ep     = (unsigned short*)alloc(SRC_ELEMS * 2);
  unsigned short* emb_bf = (unsigned short*)alloc((size_t)NSTEPS*BATCH*NE*2);
  unsigned short* W1     = (unsigned short*)alloc((size_t)N1*KX*2);
  unsigned short* WnB    = (unsigned short*)alloc((size_t)NH*KX*2);
  unsigned short* Was    = (unsigned short*)alloc((size_t)NH*NH*2);
  unsigned short* Wae    = (unsigned short*)alloc((size_t)NH*NH*2);
  float*          b1     = (float*)alloc((size_t)N1*4);
  unsigned short* x      = (unsigned short*)alloc((size_t)BATCH*KX*2);
  float*          s_f32  = (float*)alloc((size_t)BATCH*NH*4);
  float*          sWa    = (float*)alloc((size_t)BATCH*NH*4);
  float*          Y      = (float*)alloc((size_t)BATCH*N1*4);
  float*          zi     = (float*)alloc((size_t)BATCH*NH*4);
  float*          npre   = (float*)alloc((size_t)BATCH*NH*4);

  float* out         = (float*)d_out;
  float* dec_outputs = out;
  float* dec_states  = out + (size_t)NSTEPS*BATCH*NH;
  float* dec_attns   = dec_states + (size_t)NSTEPS*BATCH*NH;

  // ---- prologue ----
  k_conv_src<<<4096, 256, 0, stream>>>(src_enc, src_bf);
  k_conv_w<<<2048, 256, 0, stream>>>(Wow, Wzw, Wrw, Wnw, Waw, Wob, Wzb, Wrb,
                                     W1, WnB, Was, Wae, b1);
  k_emb<<<2048, 256, 0, stream>>>(tgt, emb_tab, emb_bf);
  k_s0<<<BATCH, 256, 0, stream>>>(src_enc, Wsw, Wsb, emb_bf, s_f32, x);
  // enc_proj = src_bf @ Wae^T + Wa_b  -> bf16 (S*B, NH)
  k_gemm<true, true><<<dim3(SB/64, NH/64), 256, 0, stream>>>(
      src_bf, NH, Wae, NH, ep, NH, Wab, NH);

  // ---- 127 sequential steps ----
  for (int t = 0; t < NSTEPS; t++) {
    // sWa = s @ Wa_s^T  (A = x's s-section, bf16)
    k_gemm<false, false><<<dim3(BATCH/64, NH/64), 256, 0, stream>>>(
        x + NE, KX, Was, NH, sWa, NH, nullptr, NH);
    // attention: scores, softmax (-> dec_attns), ci (-> x)
    k_attn<<<BATCH, 512, 0, stream>>>(ep, src_bf, sWa, vaw, slen,
                                      dec_attns + (size_t)t*BATCH*S_LEN, x);
    // Y = x @ [Wo;Wz;Wr]^T + b1
    k_gemm<false, true><<<dim3(BATCH/64, N1/64), 256, 0, stream>>>(
        x, KX, W1, KX, Y, N1, b1, KX);
    // ti out, zi, xn middle = ri*s
    k_mid<<<BATCH, 512, 0, stream>>>(Y, s_f32, dec_outputs + (size_t)t*BATCH*NH, zi, x);
    // npre = xn @ Wn^T + Wn_b
    k_gemm<false, true><<<dim3(BATCH/64, NH/64), 256, 0, stream>>>(
        x, KX, WnB, KX, npre, NH, Wnb, KX);
    // state update, record s_old, seed next x
    k_final<<<BATCH, 512, 0, stream>>>(npre, zi, s_f32,
                                       dec_states + (size_t)t*BATCH*NH, x,
                                       emb_bf + (size_t)(t+1)*BATCH*NE,
                                       (t+1) < NSTEPS ? 1 : 0);
  }
}

// Round 2
// 9611.034 us; speedup vs baseline: 1.2312x; 1.2312x over previous
//
#include <hip/hip_runtime.h>
#include <hip/hip_bf16.h>
#include <cstdint>
#include <cstddef>

namespace {

constexpr int S_LEN  = 256;
constexpr int BATCH  = 256;
constexpr int NH     = 512;
constexpr int NE     = 256;
constexpr int NSTEPS = 127;          // TGT_LEN-1
constexpr int N1     = 2048;         // [Wo;Wz;Wr;Wn_partial]
constexpr size_t SB        = (size_t)S_LEN * BATCH;   // 65536
constexpr size_t SRC_ELEMS = SB * NH;                 // 33,554,432

typedef __attribute__((ext_vector_type(8))) short  short8v;
typedef __attribute__((ext_vector_type(4))) float  float4v;
typedef unsigned short us;

constexpr int EPI_F32 = 0, EPI_EPROJ = 1, EPI_STEP1 = 2, EPI_STEP2 = 3, EPI_S0 = 4;

__device__ __forceinline__ float bf2f(us u) {
  union { unsigned int i; float f; } c; c.i = ((unsigned int)u) << 16; return c.f;
}
__device__ __forceinline__ us f2bf(float f) {
  union { float f; unsigned int i; } c; c.f = f;
  unsigned int x = c.i;
  return (us)((x + 0x7FFFu + ((x >> 16) & 1u)) >> 16);
}
// tanh(x) = 1 - 2/(e^{2x}+1): 3 VALU + 2 trans, branch-free, correct at +-inf
__device__ __forceinline__ float tanh2(float x) {
  return 1.f - 2.f * __builtin_amdgcn_rcpf(__expf(2.f * x) + 1.f);
}
__device__ __forceinline__ float sigm(float x) {
  return __builtin_amdgcn_rcpf(1.f + __expf(-x));
}

// ---------------- prologue: conversions ----------------

__global__ void k_conv_src(const float* __restrict__ src, us* __restrict__ dst) {
  size_t i = (size_t)blockIdx.x * blockDim.x + threadIdx.x;
  size_t stride = (size_t)gridDim.x * blockDim.x;
  for (size_t j = i * 4; j < SRC_ELEMS; j += stride * 4) {
    float4 v = *(const float4*)(src + j);
    dst[j+0] = f2bf(v.x); dst[j+1] = f2bf(v.y);
    dst[j+2] = f2bf(v.z); dst[j+3] = f2bf(v.w);
  }
}

// Build: W1cat[2048][1280] (rows 1536.. = Wn with s-cols zeroed), Wns[512][512],
// Was[512][512], Wae[512][512], Wsbf[512][512], bcat[2048]
__global__ void k_conv_w(const float* __restrict__ Wo, const float* __restrict__ Wz,
                         const float* __restrict__ Wr, const float* __restrict__ Wn,
                         const float* __restrict__ Wa, const float* __restrict__ Ws,
                         const float* __restrict__ Wob, const float* __restrict__ Wzb,
                         const float* __restrict__ Wrb, const float* __restrict__ Wnb,
                         us* __restrict__ W1cat, us* __restrict__ Wns,
                         us* __restrict__ Was, us* __restrict__ Wae,
                         us* __restrict__ Wsbf, float* __restrict__ bcat) {
  const int T1 = 2048 * 1280;
  const int T2 = 512 * 512;
  const int total = T1 + 4 * T2 + 2048;
  int i = blockIdx.x * blockDim.x + threadIdx.x;
  int stride = gridDim.x * blockDim.x;
  for (; i < total; i += stride) {
    int idx = i;
    if (idx < T1) {
      int row = idx / 1280, col = idx - row * 1280;
      float v;
      if      (row < 512)  v = Wo[row * 1280 + col];
      else if (row < 1024) v = Wz[(row - 512) * 1280 + col];
      else if (row < 1536) v = Wr[(row - 1024) * 1280 + col];
      else {
        int g = row - 1536;
        v = (col >= 256 && col < 768) ? 0.f : Wn[g * 1280 + col];
      }
      W1cat[idx] = f2bf(v);
    } else if ((idx -= T1) < T2) {
      int g = idx >> 9, j = idx & 511;
      Wns[idx] = f2bf(Wn[g * 1280 + 256 + j]);
    } else if ((idx -= T2) < T2) {
      int g = idx >> 9, h = idx & 511;
      Was[idx] = f2bf(Wa[g * 1024 + h]);
    } else if ((idx -= T2) < T2) {
      int g = idx >> 9, h = idx & 511;
      Wae[idx] = f2bf(Wa[g * 1024 + 512 + h]);
    } else if ((idx -= T2) < T2) {
      Wsbf[idx] = f2bf(Ws[idx]);
    } else {
      idx -= T2;
      bcat[idx] = (idx < 512) ? Wob[idx]
                : (idx < 1024) ? Wzb[idx - 512]
                : (idx < 1536) ? Wrb[idx - 1024]
                               : Wnb[idx - 1536];
    }
  }
}

__global__ void k_emb(const int* __restrict__ tgt, const float* __restrict__ table,
                      us* __restrict__ emb) {
  const int total = NSTEPS * BATCH * NE;
  int i = blockIdx.x * blockDim.x + threadIdx.x;
  int stride = gridDim.x * blockDim.x;
  for (; i < total; i += stride) {
    int e  = i & (NE - 1);
    int tb = i >> 8;            // t*BATCH + b
    int sym = tgt[tb];
    emb[i] = f2bf(table[sym * NE + e]);
  }
}

// ---------------- MFMA GEMM, 64x64 tile, BK=64, double-buffered, swizzled LDS -------
// C[m,n] = sum_k A[m,k] * B[n,k]  (B row-major [N][K], i.e. computes A @ B^T)
template<int EPI>
__global__ __launch_bounds__(256) void k_g64(
    const us* __restrict__ A0, const us* __restrict__ A1, const us* __restrict__ A2,
    const us* __restrict__ Bw, int K,
    const float* __restrict__ bias,      // EPROJ/STEP1/S0: bias; STEP2: zi
    float* __restrict__ f0, float* __restrict__ f1, float* __restrict__ f2,
    us* __restrict__ g0,
    const float* __restrict__ sf) {      // STEP1: s_f32 (read)
  constexpr bool X3 = (EPI == EPI_STEP1);
  __shared__ us As[2][4096];
  __shared__ us Bs[2][4096];
  const int tid = threadIdx.x;
  const int m0 = blockIdx.x * 64, n0 = blockIdx.y * 64;
  const int srow  = tid >> 2;            // 0..63
  const int c0    = (tid & 3) * 16;      // elem col of first 16B chunk
  const int cbyte = c0 * 2;
  const int nit   = K >> 6;
  short8v ar0, ar1, br0, br1;

  auto loadA = [&](int k0) {
    const int cc0 = k0 + c0, cc1 = cc0 + 8;
    if (X3) {
      const us* p0 = (cc0 < 256) ? A0 + (size_t)(m0 + srow) * 256 + cc0
                   : (cc0 < 768) ? A1 + (size_t)(m0 + srow) * 512 + (cc0 - 256)
                                 : A2 + (size_t)(m0 + srow) * 512 + (cc0 - 768);
      const us* p1 = (cc1 < 256) ? A0 + (size_t)(m0 + srow) * 256 + cc1
                   : (cc1 < 768) ? A1 + (size_t)(m0 + srow) * 512 + (cc1 - 256)
                                 : A2 + (size_t)(m0 + srow) * 512 + (cc1 - 768);
      ar0 = *(const short8v*)p0;
      ar1 = *(const short8v*)p1;
    } else {
      const us* p = A0 + (size_t)(m0 + srow) * K + cc0;
      ar0 = *(const short8v*)p;
      ar1 = *(const short8v*)(p + 8);
    }
    const us* q = Bw + (size_t)(n0 + srow) * K + cc0;
    br0 = *(const short8v*)q;
    br1 = *(const short8v*)(q + 8);
  };
  auto stage = [&](int buf) {
    char* ab = (char*)As + buf * 8192;
    char* bb = (char*)Bs + buf * 8192;
    const int sw = (srow & 7) << 4;
    const int o0 = srow * 128 + (cbyte ^ sw);
    const int o1 = srow * 128 + ((cbyte + 16) ^ sw);
    *(short8v*)(ab + o0) = ar0;
    *(short8v*)(ab + o1) = ar1;
    *(short8v*)(bb + o0) = br0;
    *(short8v*)(bb + o1) = br1;
  };

  const int lane = tid & 63, wave = tid >> 6;
  const int wm = (wave >> 1) * 32, wn = (wave & 1) * 32;
  const int fr = lane & 15, kq = lane >> 4;
  const int ra0 = wm + fr, ra1 = wm + 16 + fr;
  const int rb0 = wn + fr, rb1 = wn + 16 + fr;
  float4v acc00 = {0,0,0,0}, acc01 = {0,0,0,0}, acc10 = {0,0,0,0}, acc11 = {0,0,0,0};

  loadA(0);
  stage(0);
  for (int it = 0; it < nit; ++it) {
    __syncthreads();
    if (it + 1 < nit) loadA((it + 1) << 6);
    const char* ab = (const char*)As + (it & 1) * 8192;
    const char* bb = (const char*)Bs + (it & 1) * 8192;
    #pragma unroll
    for (int ks = 0; ks < 2; ++ks) {
      const int cb2 = ks * 64 + kq * 16;
      short8v a0 = *(const short8v*)(ab + ra0 * 128 + (cb2 ^ ((ra0 & 7) << 4)));
      short8v a1 = *(const short8v*)(ab + ra1 * 128 + (cb2 ^ ((ra1 & 7) << 4)));
      short8v b0 = *(const short8v*)(bb + rb0 * 128 + (cb2 ^ ((rb0 & 7) << 4)));
      short8v b1 = *(const short8v*)(bb + rb1 * 128 + (cb2 ^ ((rb1 & 7) << 4)));
      acc00 = __builtin_amdgcn_mfma_f32_16x16x32_bf16(a0, b0, acc00, 0, 0, 0);
      acc01 = __builtin_amdgcn_mfma_f32_16x16x32_bf16(a0, b1, acc01, 0, 0, 0);
      acc10 = __builtin_amdgcn_mfma_f32_16x16x32_bf16(a1, b0, acc10, 0, 0, 0);
      acc11 = __builtin_amdgcn_mfma_f32_16x16x32_bf16(a1, b1, acc11, 0, 0, 0);
    }
    if (it + 1 < nit) stage((it + 1) & 1);
  }

  #pragma unroll
  for (int am = 0; am < 2; ++am) {
    #pragma unroll
    for (int bn = 0; bn < 2; ++bn) {
      float4v a = am ? (bn ? acc11 : acc10) : (bn ? acc01 : acc00);
      #pragma unroll
      for (int r = 0; r < 4; ++r) {
        const int rowO = m0 + wm + am * 16 + kq * 4 + r;
        const int colO = n0 + wn + bn * 16 + fr;
        float v = a[r];
        if (EPI == EPI_F32) {
          f0[(size_t)rowO * 512 + colO] = v;
        } else if (EPI == EPI_S0) {
          float tv = tanh2(v + bias[colO]);
          f0[(size_t)rowO * 512 + colO] = tv;
          g0[(size_t)rowO * 512 + colO] = f2bf(tv);
        } else if (EPI == EPI_EPROJ) {
          g0[(size_t)rowO * 512 + colO] = f2bf(v + bias[colO]);
        } else if (EPI == EPI_STEP1) {
          v += bias[colO];
          const int q = colO >> 9, j = colO & 511;
          const size_t idx = (size_t)rowO * 512 + j;
          if      (q == 0) f0[idx] = v;                       // dec_outputs[t]
          else if (q == 1) f1[idx] = sigm(v);                 // zi
          else if (q == 2) g0[idx] = f2bf(sigm(v) * sf[idx]); // xn = ri*s
          else             f2[idx] = v;                       // npart (incl Wn_b)
        } else { // EPI_STEP2
          const size_t idx = (size_t)rowO * 512 + colO;
          float nv = tanh2(v + f2[idx]);
          float z  = bias[idx];         // zi
          float so = f1[idx];           // s_f32 (old)
          float sn = (1.f - z) * so + z * nv;
          f0[idx] = so;                 // dec_states[t]
          f1[idx] = sn;                 // s_f32 (new)
          g0[idx] = f2bf(sn);           // s_bf
        }
      }
    }
  }
}

// ---------------- per-step: attention (scores + softmax + context) ----------------
__global__ __launch_bounds__(512) void k_attn(
    const us* __restrict__ ep,        // (S*B, NH) bf16
    const us* __restrict__ srcb,      // (S*B, NH) bf16
    const float* __restrict__ sWa,    // (B, NH) f32
    const float* __restrict__ va,     // (NH,)
    const int* __restrict__ slen,     // (B,)
    float* __restrict__ attn_out,     // (B, S) for this t
    us* __restrict__ ci_bf) {         // (B, NH) bf16
  __shared__ float ei[S_LEN];
  __shared__ float ai[S_LEN];
  __shared__ float red[8];
  const int b = blockIdx.x, tid = threadIdx.x;
  const int lane = tid & 63, wave = tid >> 6;
  const int g0 = lane * 8;
  // hoist this lane's q and va slices into registers
  float qv[8], vv[8];
  {
    const float* qp = sWa + b * NH + g0;
    const float* vp = va + g0;
    #pragma unroll
    for (int j = 0; j < 8; j++) { qv[j] = qp[j]; vv[j] = vp[j]; }
  }
  const int len = slen[b];

  // scores: ei[s] = sum_h va[h]*tanh(ep[s,b,h] + q[h])
  for (int s = wave; s < S_LEN; s += 8) {
    short8v v = *(const short8v*)(ep + ((size_t)s * BATCH + b) * NH + g0);
    float acc = 0.f;
    #pragma unroll
    for (int j = 0; j < 8; j++)
      acc += tanh2(bf2f((us)v[j]) + qv[j]) * vv[j];
    #pragma unroll
    for (int off = 32; off > 0; off >>= 1) acc += __shfl_xor(acc, off, 64);
    if (lane == 0) ei[s] = (s < len) ? acc : -3.0e38f;
  }
  __syncthreads();

  // softmax over s
  float e = (tid < S_LEN) ? ei[tid] : -3.0e38f;
  float m = e;
  #pragma unroll
  for (int off = 32; off > 0; off >>= 1) m = fmaxf(m, __shfl_xor(m, off, 64));
  if (lane == 0) red[wave] = m;
  __syncthreads();
  m = red[0];
  #pragma unroll
  for (int w = 1; w < 8; w++) m = fmaxf(m, red[w]);
  float p = (tid < S_LEN) ? __expf(e - m) : 0.f;
  float sum = p;
  #pragma unroll
  for (int off = 32; off > 0; off >>= 1) sum += __shfl_xor(sum, off, 64);
  __syncthreads();
  if (lane == 0) red[wave] = sum;
  __syncthreads();
  float tot = red[0];
  #pragma unroll
  for (int w = 1; w < 8; w++) tot += red[w];
  float inv = __builtin_amdgcn_rcpf(tot);
  if (tid < S_LEN) {
    float a = p * inv;
    ai[tid] = a;
    attn_out[(size_t)b * S_LEN + tid] = a;
  }
  __syncthreads();

  // context: ci[h] = sum_s ai[s]*src[s,b,h]
  float acc = 0.f;
  const us* sp = srcb + (size_t)b * NH + tid;
  #pragma unroll 8
  for (int s = 0; s < S_LEN; s++) acc += ai[s] * bf2f(sp[(size_t)s * BATCH * NH]);
  ci_bf[b * NH + tid] = f2bf(acc);
}

} // namespace

extern "C" void kernel_launch(void* const* d_in, const int* in_sizes, int n_in,
                              void* d_out, int out_size, void* d_ws, size_t ws_size,
                              hipStream_t stream) {
  const float* src_enc  = (const float*)d_in[0];
  const int*   tgt      = (const int*)d_in[1];
  const int*   slen     = (const int*)d_in[2];
  const float* emb_tab  = (const float*)d_in[3];
  const float* Wsw      = (const float*)d_in[4];
  const float* Wsb      = (const float*)d_in[5];
  const float* Wzw      = (const float*)d_in[6];
  const float* Wzb      = (const float*)d_in[7];
  const float* Wrw      = (const float*)d_in[8];
  const float* Wrb      = (const float*)d_in[9];
  const float* Wnw      = (const float*)d_in[10];
  const float* Wnb      = (const float*)d_in[11];
  const float* Waw      = (const float*)d_in[12];
  const float* Wab      = (const float*)d_in[13];
  const float* vaw      = (const float*)d_in[14];
  const float* Wow      = (const float*)d_in[15];
  const float* Wob      = (const float*)d_in[16];

  char* ws = (char*)d_ws;
  size_t off = 0;
  auto alloc = [&](size_t bytes) -> void* {
    void* p = ws + off;
    off = (off + bytes + 255) & ~(size_t)255;
    return p;
  };
  us*    src_bf = (us*)alloc(SRC_ELEMS * 2);
  us*    ep     = (us*)alloc(SRC_ELEMS * 2);
  us*    emb_bf = (us*)alloc((size_t)NSTEPS * BATCH * NE * 2);
  us*    W1cat  = (us*)alloc((size_t)N1 * 1280 * 2);
  us*    Wns    = (us*)alloc((size_t)512 * 512 * 2);
  us*    Was    = (us*)alloc((size_t)512 * 512 * 2);
  us*    Wae    = (us*)alloc((size_t)512 * 512 * 2);
  us*    Wsbf   = (us*)alloc((size_t)512 * 512 * 2);
  float* bcat   = (float*)alloc((size_t)N1 * 4);
  float* s_f32  = (float*)alloc((size_t)BATCH * NH * 4);
  us*    s_bf   = (us*)alloc((size_t)BATCH * NH * 2);
  float* sWa    = (float*)alloc((size_t)BATCH * NH * 4);
  float* zi     = (float*)alloc((size_t)BATCH * NH * 4);
  float* npart  = (float*)alloc((size_t)BATCH * NH * 4);
  us*    xn_bf  = (us*)alloc((size_t)BATCH * NH * 2);
  us*    ci_bf  = (us*)alloc((size_t)BATCH * NH * 2);

  float* out         = (float*)d_out;
  float* dec_outputs = out;
  float* dec_states  = out + (size_t)NSTEPS * BATCH * NH;
  float* dec_attns   = dec_states + (size_t)NSTEPS * BATCH * NH;

  // ---- prologue ----
  k_conv_src<<<4096, 256, 0, stream>>>(src_enc, src_bf);
  k_conv_w<<<2048, 256, 0, stream>>>(Wow, Wzw, Wrw, Wnw, Waw, Wsw,
                                     Wob, Wzb, Wrb, Wnb,
                                     W1cat, Wns, Was, Wae, Wsbf, bcat);
  k_emb<<<2048, 256, 0, stream>>>(tgt, emb_tab, emb_bf);
  // s0 = tanh(src_enc[0] @ Ws^T + Ws_b)
  k_g64<EPI_S0><<<dim3(4, 8), 256, 0, stream>>>(
      src_bf, nullptr, nullptr, Wsbf, 512, Wsb, s_f32, nullptr, nullptr, s_bf, nullptr);
  // enc_proj = src @ Wae^T + Wa_b  (bf16)
  k_g64<EPI_EPROJ><<<dim3(1024, 8), 256, 0, stream>>>(
      src_bf, nullptr, nullptr, Wae, 512, Wab, nullptr, nullptr, nullptr, ep, nullptr);

  // ---- 127 sequential steps, 4 kernels each ----
  for (int t = 0; t < NSTEPS; t++) {
    // sWa = s @ Was^T
    k_g64<EPI_F32><<<dim3(4, 8), 256, 0, stream>>>(
        s_bf, nullptr, nullptr, Was, 512, nullptr, sWa, nullptr, nullptr, nullptr, nullptr);
    // attention: scores, softmax -> dec_attns, ci -> ci_bf
    k_attn<<<BATCH, 512, 0, stream>>>(ep, src_bf, sWa, vaw, slen,
                                      dec_attns + (size_t)t * BATCH * S_LEN, ci_bf);
    // Y = [emb|s|ci] @ W1cat^T + bcat: dec_out | zi | xn=ri*s | npart
    k_g64<EPI_STEP1><<<dim3(4, 32), 256, 0, stream>>>(
        emb_bf + (size_t)t * BATCH * NE, s_bf, ci_bf, W1cat, 1280, bcat,
        dec_outputs + (size_t)t * BATCH * NH, zi, npart, xn_bf, s_f32);
    // npre = npart + xn @ Wns^T; s update epilogue
    k_g64<EPI_STEP2><<<dim3(4, 8), 256, 0, stream>>>(
        xn_bf, nullptr, nullptr, Wns, 512, zi,
        dec_states + (size_t)t * BATCH * NH, s_f32, npart, s_bf, nullptr);
  }
}